// Round 4
// baseline (619.611 us; speedup 1.0000x reference)
//
#include <hip/hip_runtime.h>
#include <math.h>

#define H 256
#define HEADS 4
#define BM 64
#define BK 32
#define TM 8
#define TN 8

// ---------------------------------------------------------------------------
// Kernel 1: scores[N,4] = tanh(x @ W1 + b1) @ W2
// Fused so the [N,256] hidden tensor never hits HBM.
// Block: 256 threads = 8 (ty, row-groups) x 32 (tx, col-groups).
// Each thread owns an 8x8 micro-tile of h; epilogue folds W2 and reduces
// across tx (a 32-lane half-wave) via shfl_xor.
// fp32 vector-ALU path (no fp32 MFMA on CDNA4). Baseline correctness oracle;
// split-bf16 MFMA planned once a validated baseline exists.
// ---------------------------------------------------------------------------
__global__ __launch_bounds__(256, 2)
void scores_kernel(const float* __restrict__ x, const float* __restrict__ W1,
                   const float* __restrict__ b1, const float* __restrict__ W2,
                   float* __restrict__ scores, int N)
{
    __shared__ float sX[BK][BM];     // transposed x tile: sX[k][r]
    __shared__ float sW[BK][H];      // W1 tile: sW[k][c]

    const int tid = threadIdx.x;
    const int tx = tid & 31;
    const int ty = tid >> 5;
    const int row0 = blockIdx.x * BM;

    float acc[TM][TN];
    #pragma unroll
    for (int r = 0; r < TM; ++r)
        #pragma unroll
        for (int c = 0; c < TN; ++c) acc[r][c] = 0.f;

    for (int k0 = 0; k0 < H; k0 += BK) {
        // stage x tile (64 rows x 32 k) -> transposed. 512 float4, 2/thread.
        #pragma unroll
        for (int it = 0; it < 2; ++it) {
            int f  = it * 256 + tid;
            int r  = f >> 3;
            int kq = (f & 7) * 4;
            int row = row0 + r;
            float4 v = make_float4(0.f, 0.f, 0.f, 0.f);
            if (row < N) v = *(const float4*)(x + (size_t)row * H + k0 + kq);
            sX[kq + 0][r] = v.x; sX[kq + 1][r] = v.y;
            sX[kq + 2][r] = v.z; sX[kq + 3][r] = v.w;
        }
        // stage W1 tile (32 k-rows x 256 cols). 2048 float4, 8/thread.
        #pragma unroll
        for (int it = 0; it < 8; ++it) {
            int f  = it * 256 + tid;
            int k  = f >> 6;
            int c4 = (f & 63) * 4;
            *(float4*)(&sW[k][c4]) = *(const float4*)(W1 + (size_t)(k0 + k) * H + c4);
        }
        __syncthreads();

        #pragma unroll
        for (int k = 0; k < BK; ++k) {
            float xr[TM], wc[TN];
            #pragma unroll
            for (int r = 0; r < TM; ++r) xr[r] = sX[k][ty * TM + r];   // broadcast
            #pragma unroll
            for (int c = 0; c < TN; ++c) wc[c] = sW[k][tx * TN + c];   // 2x b128, 32B stride
            #pragma unroll
            for (int r = 0; r < TM; ++r)
                #pragma unroll
                for (int c = 0; c < TN; ++c)
                    acc[r][c] = fmaf(xr[r], wc[c], acc[r][c]);
        }
        __syncthreads();
    }

    // epilogue: h = tanh(acc + b1[col]); ps[r][head] += h * W2[col][head]
    float ps[TM][HEADS];
    #pragma unroll
    for (int r = 0; r < TM; ++r)
        #pragma unroll
        for (int hh = 0; hh < HEADS; ++hh) ps[r][hh] = 0.f;

    #pragma unroll
    for (int c = 0; c < TN; ++c) {
        int col = tx * TN + c;
        float bb = b1[col];
        float w2[HEADS];
        #pragma unroll
        for (int hh = 0; hh < HEADS; ++hh) w2[hh] = W2[col * HEADS + hh];
        #pragma unroll
        for (int r = 0; r < TM; ++r) {
            float hv = tanhf(acc[r][c] + bb);
            #pragma unroll
            for (int hh = 0; hh < HEADS; ++hh)
                ps[r][hh] = fmaf(hv, w2[hh], ps[r][hh]);
        }
    }
    // reduce across tx (masks <32 keep the xor within each 32-lane half-wave)
    #pragma unroll
    for (int m = 16; m >= 1; m >>= 1) {
        #pragma unroll
        for (int r = 0; r < TM; ++r)
            #pragma unroll
            for (int hh = 0; hh < HEADS; ++hh)
                ps[r][hh] += __shfl_xor(ps[r][hh], m, 64);
    }
    if (tx == 0) {
        #pragma unroll
        for (int r = 0; r < TM; ++r) {
            int row = row0 + ty * TM + r;
            if (row < N) {
                float4 o = make_float4(ps[r][0], ps[r][1], ps[r][2], ps[r][3]);
                *(float4*)(scores + (size_t)row * HEADS) = o;   // 16B-aligned
            }
        }
    }
}

// ---------------------------------------------------------------------------
// Block-wide float4 reductions (max / sum) for 256-thread blocks.
// ---------------------------------------------------------------------------
__device__ inline float4 blockMax4(float4 v, float4* lds) {
    #pragma unroll
    for (int m = 32; m >= 1; m >>= 1) {
        v.x = fmaxf(v.x, __shfl_xor(v.x, m, 64));
        v.y = fmaxf(v.y, __shfl_xor(v.y, m, 64));
        v.z = fmaxf(v.z, __shfl_xor(v.z, m, 64));
        v.w = fmaxf(v.w, __shfl_xor(v.w, m, 64));
    }
    int wid = threadIdx.x >> 6, lane = threadIdx.x & 63;
    if (lane == 0) lds[wid] = v;
    __syncthreads();
    float4 r = lds[0];
    #pragma unroll
    for (int w = 1; w < 4; ++w) {
        float4 o = lds[w];
        r.x = fmaxf(r.x, o.x); r.y = fmaxf(r.y, o.y);
        r.z = fmaxf(r.z, o.z); r.w = fmaxf(r.w, o.w);
    }
    __syncthreads();
    return r;
}

__device__ inline float4 blockSum4(float4 v, float4* lds) {
    #pragma unroll
    for (int m = 32; m >= 1; m >>= 1) {
        v.x += __shfl_xor(v.x, m, 64);
        v.y += __shfl_xor(v.y, m, 64);
        v.z += __shfl_xor(v.z, m, 64);
        v.w += __shfl_xor(v.w, m, 64);
    }
    int wid = threadIdx.x >> 6, lane = threadIdx.x & 63;
    if (lane == 0) lds[wid] = v;
    __syncthreads();
    float4 r = lds[0];
    #pragma unroll
    for (int w = 1; w < 4; ++w) {
        float4 o = lds[w];
        r.x += o.x; r.y += o.y; r.z += o.z; r.w += o.w;
    }
    __syncthreads();
    return r;
}

// ---------------------------------------------------------------------------
// Kernel 2: per-graph segment softmax stats, folded into per-node wbar:
//   wbar[i] = (1/HEADS) * sum_h exp(scores[i,h]-m[g,h]) / Z[g,h]
// (pooled.mean(axis=1) folds into a single per-node scalar weight.)
// One block per graph; batch is sorted so bounds come from binary search.
// ---------------------------------------------------------------------------
__global__ __launch_bounds__(256)
void segsoftmax_kernel(const float* __restrict__ scores, const int* __restrict__ batch,
                       float* __restrict__ wbar, int N)
{
    const int g = blockIdx.x;
    const int tid = threadIdx.x;
    __shared__ int sB[2];
    __shared__ float4 sRed[4];

    if (tid < 2) {
        int target = g + tid, lo = 0, hi = N;
        while (lo < hi) { int mid = (lo + hi) >> 1; if (batch[mid] < target) lo = mid + 1; else hi = mid; }
        sB[tid] = lo;
    }
    __syncthreads();
    const int start = sB[0], end = sB[1];

    // pass 1: per-head max
    float4 mv = make_float4(-INFINITY, -INFINITY, -INFINITY, -INFINITY);
    for (int i = start + tid; i < end; i += 256) {
        float4 s = *(const float4*)(scores + (size_t)i * HEADS);
        mv.x = fmaxf(mv.x, s.x); mv.y = fmaxf(mv.y, s.y);
        mv.z = fmaxf(mv.z, s.z); mv.w = fmaxf(mv.w, s.w);
    }
    mv = blockMax4(mv, sRed);

    // pass 2: per-head sum of exp
    float4 sv = make_float4(0.f, 0.f, 0.f, 0.f);
    for (int i = start + tid; i < end; i += 256) {
        float4 s = *(const float4*)(scores + (size_t)i * HEADS);
        sv.x += expf(s.x - mv.x); sv.y += expf(s.y - mv.y);
        sv.z += expf(s.z - mv.z); sv.w += expf(s.w - mv.w);
    }
    sv = blockSum4(sv, sRed);
    float4 rz;
    rz.x = sv.x > 0.f ? 1.f / sv.x : 0.f;
    rz.y = sv.y > 0.f ? 1.f / sv.y : 0.f;
    rz.z = sv.z > 0.f ? 1.f / sv.z : 0.f;
    rz.w = sv.w > 0.f ? 1.f / sv.w : 0.f;

    // pass 3: wbar
    for (int i = start + tid; i < end; i += 256) {
        float4 s = *(const float4*)(scores + (size_t)i * HEADS);
        float w = expf(s.x - mv.x) * rz.x + expf(s.y - mv.y) * rz.y +
                  expf(s.z - mv.z) * rz.z + expf(s.w - mv.w) * rz.w;
        wbar[i] = 0.25f * w;
    }
}

// ---------------------------------------------------------------------------
// Kernel 3: out[g, c] = sum_{i in segment g} wbar[i] * x[i, c]
// One block (256 threads = 256 channels) per graph. HBM-bound; 8 independent
// FMA chains keep 8 loads in flight per lane to cover ~900cy HBM latency
// at only 2 blocks/CU occupancy. Empty segments write 0 (matches reference).
// ---------------------------------------------------------------------------
__global__ __launch_bounds__(256)
void pool_kernel(const float* __restrict__ x, const float* __restrict__ wbar,
                 const int* __restrict__ batch, float* __restrict__ out, int N)
{
    const int g = blockIdx.x;
    const int c = threadIdx.x;
    __shared__ int sB[2];
    if (threadIdx.x < 2) {
        int target = g + (int)threadIdx.x, lo = 0, hi = N;
        while (lo < hi) { int mid = (lo + hi) >> 1; if (batch[mid] < target) lo = mid + 1; else hi = mid; }
        sB[threadIdx.x] = lo;
    }
    __syncthreads();
    const int start = sB[0], end = sB[1];

    float a[8];
    #pragma unroll
    for (int j = 0; j < 8; ++j) a[j] = 0.f;

    int i = start;
    for (; i + 8 <= end; i += 8) {
        #pragma unroll
        for (int j = 0; j < 8; ++j)
            a[j] = fmaf(wbar[i + j], x[(size_t)(i + j) * H + c], a[j]);
    }
    for (; i < end; ++i)
        a[0] = fmaf(wbar[i], x[(size_t)i * H + c], a[0]);

    out[(size_t)g * H + c] = ((a[0] + a[1]) + (a[2] + a[3])) +
                             ((a[4] + a[5]) + (a[6] + a[7]));
}

// ---------------------------------------------------------------------------
extern "C" void kernel_launch(void* const* d_in, const int* in_sizes, int n_in,
                              void* d_out, int out_size, void* d_ws, size_t ws_size,
                              hipStream_t stream)
{
    const float* x     = (const float*)d_in[0];
    const int*   batch = (const int*)d_in[1];
    const float* W1    = (const float*)d_in[2];
    const float* b1    = (const float*)d_in[3];
    const float* W2    = (const float*)d_in[4];
    float*       out   = (float*)d_out;

    const int N = in_sizes[1];          // batch has N elements
    const int G = out_size / H;         // out is [G, H]

    // workspace: scores [N,4] f32 then wbar [N] f32  (~4 MB total)
    float* scores = (float*)d_ws;
    float* wbar   = scores + (size_t)N * HEADS;

    dim3 blk(256);
    scores_kernel<<<dim3((N + BM - 1) / BM), blk, 0, stream>>>(x, W1, b1, W2, scores, N);
    segsoftmax_kernel<<<dim3(G), blk, 0, stream>>>(scores, batch, wbar, N);
    pool_kernel<<<dim3(G), blk, 0, stream>>>(x, wbar, batch, out, N);
}